// Round 4
// baseline (667.831 us; speedup 1.0000x reference)
//
#include <hip/hip_runtime.h>
#include <cstdint>

#define P2 2654435761u
#define P3 805459861u
#define HMASK 524287u

typedef float f2v __attribute__((ext_vector_type(2)));

// int(16 * exp((ln2048-ln16)/15)**l), hand-verified vs IEEE-double reference.
// res[7]=153 (153.987), res[15]=2048 (2048.0000000000036, min-clamped).
__constant__ int c_res[16] = {16, 22, 30, 42, 58, 80, 111, 153,
                              212, 294, 406, 561, 776, 1072, 1482, 2048};

// L1-bypass load: relaxed agent-scope atomic load emits sc0 (no L1 line
// allocation; request goes TA->TCC). Probes whether the ~2.4 cyc/line TCP
// cost is miss-allocation overhead vs intrinsic address serialization.
__device__ __forceinline__ float2 ld_l1bypass(const float2* __restrict__ p) {
    unsigned long long v = __hip_atomic_load(
        reinterpret_cast<const unsigned long long*>(p),
        __ATOMIC_RELAXED, __HIP_MEMORY_SCOPE_AGENT);
    union { unsigned long long u; float2 f; } cv; cv.u = v;
    return cv.f;
}

// One thread per (point, level), t = i*16 + l (point-major: coalesced store,
// 8 independent gathers/thread, 16M threads for TLP). Round-2 structure.
__global__ __launch_bounds__(256) void hash_enc_kernel(
    const float* __restrict__ pos, const float2* __restrict__ tbl,
    float2* __restrict__ out, int n)
{
    __shared__ int sres[16];
    if (threadIdx.x < 16) sres[threadIdx.x] = c_res[threadIdx.x];
    __syncthreads();

    int t = blockIdx.x * 256 + threadIdx.x;
    int i = t >> 4;
    int l = t & 15;
    if (i >= n) return;

    // 16 consecutive lanes share these 12 bytes -> coalesced/L1 broadcast
    float x = (pos[3 * i + 0] + 1.0f) * 0.5f;
    float y = (pos[3 * i + 1] + 1.0f) * 0.5f;
    float z = (pos[3 * i + 2] + 1.0f) * 0.5f;

    const int rm1 = sres[l] - 1;
    const float rf = (float)rm1;
    float sx = x * rf, sy = y * rf, sz = z * rf;
    float fx = floorf(sx), fy = floorf(sy), fz = floorf(sz);
    float wx = sx - fx, wy = sy - fy, wz = sz - fz;
    // p in [0,1] -> base corner already in [0, rm1]; only +1 needs clamp
    int x0 = (int)fx, y0 = (int)fy, z0 = (int)fz;
    int x1c = min(x0 + 1, rm1), y1c = min(y0 + 1, rm1), z1c = min(z0 + 1, rm1);

    // low 19 bits of the int64 hash == low 19 bits of the uint32 hash
    uint32_t hx0 = (uint32_t)x0,       hx1 = (uint32_t)x1c;
    uint32_t hy0 = (uint32_t)y0 * P2,  hy1 = (uint32_t)y1c * P2;
    uint32_t hz0 = (uint32_t)z0 * P3,  hz1 = (uint32_t)z1c * P3;

    // 8 independent L1-bypass gathers, issued back-to-back
    float2 c000 = ld_l1bypass(tbl + ((hx0 ^ hy0 ^ hz0) & HMASK));
    float2 c001 = ld_l1bypass(tbl + ((hx0 ^ hy0 ^ hz1) & HMASK));
    float2 c010 = ld_l1bypass(tbl + ((hx0 ^ hy1 ^ hz0) & HMASK));
    float2 c011 = ld_l1bypass(tbl + ((hx0 ^ hy1 ^ hz1) & HMASK));
    float2 c100 = ld_l1bypass(tbl + ((hx1 ^ hy0 ^ hz0) & HMASK));
    float2 c101 = ld_l1bypass(tbl + ((hx1 ^ hy0 ^ hz1) & HMASK));
    float2 c110 = ld_l1bypass(tbl + ((hx1 ^ hy1 ^ hz0) & HMASK));
    float2 c111 = ld_l1bypass(tbl + ((hx1 ^ hy1 ^ hz1) & HMASK));

    float ux = 1.0f - wx, uy = 1.0f - wy, uz = 1.0f - wz;
    float w00 = ux * uy, w01 = ux * wy, w10 = wx * uy, w11 = wx * wy;
    float f0, f1;
    f0  = (w00 * uz) * c000.x; f1  = (w00 * uz) * c000.y;
    f0 += (w00 * wz) * c001.x; f1 += (w00 * wz) * c001.y;
    f0 += (w01 * uz) * c010.x; f1 += (w01 * uz) * c010.y;
    f0 += (w01 * wz) * c011.x; f1 += (w01 * wz) * c011.y;
    f0 += (w10 * uz) * c100.x; f1 += (w10 * uz) * c100.y;
    f0 += (w10 * wz) * c101.x; f1 += (w10 * wz) * c101.y;
    f0 += (w11 * uz) * c110.x; f1 += (w11 * uz) * c110.y;
    f0 += (w11 * wz) * c111.x; f1 += (w11 * wz) * c111.y;

    // non-temporal: keep the 131 MB output stream from evicting the table in L2
    f2v v; v.x = f0; v.y = f1;
    __builtin_nontemporal_store(v, reinterpret_cast<f2v*>(out) + t);
}

extern "C" void kernel_launch(void* const* d_in, const int* in_sizes, int n_in,
                              void* d_out, int out_size, void* d_ws, size_t ws_size,
                              hipStream_t stream) {
    const float* pos = (const float*)d_in[0];
    const float2* tbl = (const float2*)d_in[1];
    float2* out = (float2*)d_out;
    int n = in_sizes[0] / 3;
    long long total = (long long)n * 16;
    hash_enc_kernel<<<(unsigned)((total + 255) / 256), 256, 0, stream>>>(
        pos, tbl, out, n);
}